// Round 7
// baseline (754.827 us; speedup 1.0000x reference)
//
#include <hip/hip_runtime.h>
#include <math.h>

#define N_NODES 50000
#define E_EDGES 800000
#define ET (E_EDGES + N_NODES)   // edges + self loops
#define L_LAYERS 4
#define NB_SCAN ((N_NODES + 255) / 256)   // 196

typedef __attribute__((ext_vector_type(8))) short short8;
typedef __attribute__((ext_vector_type(4))) float f32x4;

__device__ __forceinline__ float gelu_f(float x) {
    return 0.5f * x * (1.0f + erff(x * 0.70710678118654752f));
}

// ---------------- graph preprocessing ----------------

__global__ __launch_bounds__(256) void count_pos(const int* __restrict__ ecol,
                                                 int* __restrict__ cnt,
                                                 int* __restrict__ aux) {
    int e = blockIdx.x * 256 + threadIdx.x;
    if (e >= ET) return;
    int c = (e < E_EDGES) ? ecol[e] : (e - E_EDGES);
    aux[e] = atomicAdd(&cnt[c], 1);
}

__global__ __launch_bounds__(256) void scan_part1(const int* __restrict__ cnt,
                                                  int* __restrict__ bsum) {
    __shared__ int red[256];
    int t = threadIdx.x;
    int i = blockIdx.x * 256 + t;
    red[t] = (i < N_NODES) ? cnt[i] : 0;
    __syncthreads();
#pragma unroll
    for (int off = 128; off; off >>= 1) {
        if (t < off) red[t] += red[t + off];
        __syncthreads();
    }
    if (t == 0) bsum[blockIdx.x] = red[0];
}

__global__ __launch_bounds__(256) void scan_part2(int* __restrict__ bsum) {
    __shared__ int sh[256];
    int t = threadIdx.x;
    int v = (t < NB_SCAN) ? bsum[t] : 0;
    sh[t] = v;
    __syncthreads();
    for (int off = 1; off < 256; off <<= 1) {
        int u = (t >= off) ? sh[t - off] : 0;
        __syncthreads();
        sh[t] += u;
        __syncthreads();
    }
    if (t < NB_SCAN) bsum[t] = sh[t] - v;   // exclusive
}

__global__ __launch_bounds__(256) void scan_part3(const int* __restrict__ cnt,
                                                  const int* __restrict__ bsum,
                                                  int* __restrict__ ptrb,
                                                  float* __restrict__ dinv) {
    __shared__ int sh[256];
    int t = threadIdx.x;
    int i = blockIdx.x * 256 + t;
    int v = (i < N_NODES) ? cnt[i] : 0;
    sh[t] = v;
    __syncthreads();
    for (int off = 1; off < 256; off <<= 1) {
        int u = (t >= off) ? sh[t - off] : 0;
        __syncthreads();
        sh[t] += u;
        __syncthreads();
    }
    int excl = sh[t] - v + bsum[blockIdx.x];
    if (i < N_NODES) {
        ptrb[i] = excl;
        dinv[i] = rsqrtf((float)v);   // deg >= 1 (self loop)
    }
    if (i == N_NODES - 1) ptrb[N_NODES] = excl + v;
}

__global__ __launch_bounds__(256) void bucket(const int* __restrict__ erow,
                                              const int* __restrict__ ecol,
                                              const int* __restrict__ aux,
                                              const int* __restrict__ ptrb,
                                              const float* __restrict__ dinv,
                                              int2* __restrict__ epack) {
    int e = blockIdx.x * 256 + threadIdx.x;
    if (e >= ET) return;
    int r, c;
    if (e < E_EDGES) { r = erow[e]; c = ecol[e]; }
    else             { r = e - E_EDGES; c = r; }
    int pos = ptrb[c] + aux[e];
    epack[pos] = make_int2(r, __float_as_int(dinv[r] * dinv[c]));
}

// ---------------- MFMA GEMM (bf16 hi/lo split, f32-class accuracy) ----------------
// C[M,128] = A[M,K] @ Wcat[K,128], K in {64,128}, via 3-term split:
//   D = Ahi*Whi + Ahi*Wlo + Alo*Whi   (error ~2^-16 rel; lo*lo dropped)
// mode 0: O1 = A@W1               (GCN h2, no bias)
// mode 1: O1 = A@W1+b1 (cols 0-63), O2 = A@W2+b2, ta = O2 @ avec  (GNA dual)
// Fragment layouts (verified, cdna_hip_programming §3):
//   A[m=lane&15][k=quad*8+j]; B[k=quad*8+j][n=lane&15]; C: col=lane&15, row=quad*4+reg.

#define AIDX(kq, row, j) ((kq) * 520 + (row) * 8 + (j))          // pad 8/kq: bank-spread
#define WIDX(nt, kq, n, j) ((nt) * 1032 + ((kq) * 16 + (n)) * 8 + (j))

__global__ __launch_bounds__(256, 3) void gemm_mfma(
    const float* __restrict__ A, int Kfull,
    const float* __restrict__ W1, const float* __restrict__ W2,
    const float* __restrict__ b1, const float* __restrict__ b2,
    const float* __restrict__ avec,
    float* __restrict__ O1, float* __restrict__ O2, float* __restrict__ ta,
    int mode) {
    __shared__ __align__(16) unsigned short Ahi[8 * 520], Alo[8 * 520];     // 8.3 KB each
    __shared__ __align__(16) unsigned short Whi[8 * 1032], Wlo[8 * 1032];   // 16.5 KB each
    int tid = threadIdx.x;
    int w   = tid >> 6;          // wave 0..3 -> rows 16w..16w+15
    int l   = tid & 63;
    int lq  = l >> 4;            // quad
    int ln  = l & 15;
    int m0  = blockIdx.x * 64;

    f32x4 acc[8];
#pragma unroll
    for (int i = 0; i < 8; ++i) acc[i] = (f32x4){0.f, 0.f, 0.f, 0.f};

    const int nchunk = Kfull >> 6;
    for (int kc = 0; kc < nchunk; ++kc) {
        // ---- stage A chunk (64 rows x 64 k), split to bf16 hi/lo ----
#pragma unroll
        for (int it = 0; it < 4; ++it) {
            int row = it * 16 + (tid >> 4);
            int kf  = (tid & 15) * 4;
            int gr  = m0 + row;
            float4 v = make_float4(0.f, 0.f, 0.f, 0.f);
            if (gr < N_NODES)
                v = *(const float4*)(A + (size_t)gr * Kfull + kc * 64 + kf);
            float xs[4] = {v.x, v.y, v.z, v.w};
            unsigned short h[4], lo[4];
#pragma unroll
            for (int c = 0; c < 4; ++c) {
                unsigned u = __float_as_uint(xs[c]);
                h[c] = (unsigned short)(u >> 16);
                float hif = __uint_as_float(u & 0xffff0000u);
                lo[c] = (unsigned short)(__float_as_uint(xs[c] - hif) >> 16);
            }
            int kq = kf >> 3, j = kf & 7;
            *(ushort4*)&Ahi[AIDX(kq, row, j)] = make_ushort4(h[0], h[1], h[2], h[3]);
            *(ushort4*)&Alo[AIDX(kq, row, j)] = make_ushort4(lo[0], lo[1], lo[2], lo[3]);
        }
        // ---- stage W chunk (64 k x 128 n) in B-fragment layout ----
#pragma unroll
        for (int it = 0; it < 8; ++it) {
            int k = it * 8 + (tid >> 5);
            int n = (tid & 31) * 4;
            float4 v;
            if (mode == 0) {
                v = *(const float4*)(W1 + (size_t)(kc * 64 + k) * 128 + n);
            } else {
                if (n < 64) v = *(const float4*)(W1 + (size_t)k * 64 + n);
                else        v = *(const float4*)(W2 + (size_t)k * 64 + (n - 64));
            }
            int nt = n >> 4, n15 = n & 15, kq = k >> 3, j = k & 7;
            float xs[4] = {v.x, v.y, v.z, v.w};
#pragma unroll
            for (int c = 0; c < 4; ++c) {
                unsigned u = __float_as_uint(xs[c]);
                Whi[WIDX(nt, kq, n15 + c, j)] = (unsigned short)(u >> 16);
                float hif = __uint_as_float(u & 0xffff0000u);
                Wlo[WIDX(nt, kq, n15 + c, j)] =
                    (unsigned short)(__float_as_uint(xs[c] - hif) >> 16);
            }
        }
        __syncthreads();
        // ---- MFMA: 8 col-tiles x 2 k-steps x 3 terms ----
        short8 ah[2], al[2];
#pragma unroll
        for (int s = 0; s < 2; ++s) {
            int kq = s * 4 + lq;
            ah[s] = *(short8*)&Ahi[AIDX(kq, w * 16 + ln, 0)];
            al[s] = *(short8*)&Alo[AIDX(kq, w * 16 + ln, 0)];
        }
#pragma unroll
        for (int nt = 0; nt < 8; ++nt) {
#pragma unroll
            for (int s = 0; s < 2; ++s) {
                int kq = s * 4 + lq;
                short8 wh = *(short8*)&Whi[WIDX(nt, kq, ln, 0)];
                short8 wl = *(short8*)&Wlo[WIDX(nt, kq, ln, 0)];
                acc[nt] = __builtin_amdgcn_mfma_f32_16x16x32_bf16(ah[s], wh, acc[nt], 0, 0, 0);
                acc[nt] = __builtin_amdgcn_mfma_f32_16x16x32_bf16(ah[s], wl, acc[nt], 0, 0, 0);
                acc[nt] = __builtin_amdgcn_mfma_f32_16x16x32_bf16(al[s], wh, acc[nt], 0, 0, 0);
            }
        }
        __syncthreads();
    }

    if (mode == 0) {
#pragma unroll
        for (int nt = 0; nt < 8; ++nt) {
            int col = nt * 16 + ln;
#pragma unroll
            for (int r = 0; r < 4; ++r) {
                int row = m0 + w * 16 + lq * 4 + r;
                if (row < N_NODES) O1[(size_t)row * 128 + col] = acc[nt][r];
            }
        }
    } else {
        float pa[4] = {0.f, 0.f, 0.f, 0.f};
#pragma unroll
        for (int nt = 0; nt < 4; ++nt) {
            int col = nt * 16 + ln;
            float bb = b1[col];
#pragma unroll
            for (int r = 0; r < 4; ++r) {
                int row = m0 + w * 16 + lq * 4 + r;
                if (row < N_NODES) O1[(size_t)row * 64 + col] = acc[nt][r] + bb;
            }
        }
#pragma unroll
        for (int nt = 4; nt < 8; ++nt) {
            int col = (nt - 4) * 16 + ln;
            float bb = b2[col];
            float av = avec[col];
#pragma unroll
            for (int r = 0; r < 4; ++r) {
                float t2 = acc[nt][r] + bb;
                int row = m0 + w * 16 + lq * 4 + r;
                if (row < N_NODES) O2[(size_t)row * 64 + col] = t2;
                pa[r] += t2 * av;
            }
        }
#pragma unroll
        for (int r = 0; r < 4; ++r) {
            pa[r] += __shfl_xor(pa[r], 1);
            pa[r] += __shfl_xor(pa[r], 2);
            pa[r] += __shfl_xor(pa[r], 4);
            pa[r] += __shfl_xor(pa[r], 8);
            int row = m0 + w * 16 + lq * 4 + r;
            if (ln == 0 && row < N_NODES) ta[row] = pa[r];
        }
    }
}

// ---------------- edge aggregation (one wave per dst) ----------------

__global__ __launch_bounds__(256) void agg128(const float* __restrict__ h2,
                                              const int* __restrict__ ptrb,
                                              const int2* __restrict__ epack,
                                              const float* __restrict__ bias,
                                              float* __restrict__ out,
                                              int apply_gelu) {
    int dst  = (blockIdx.x * 256 + threadIdx.x) >> 6;
    int lane = threadIdx.x & 63;
    if (dst >= N_NODES) return;
    int sub = lane >> 5;
    int fl  = lane & 31;
    int p0 = ptrb[dst], p1 = ptrb[dst + 1];
    float4 acc[4];
#pragma unroll
    for (int k = 0; k < 4; ++k) acc[k] = make_float4(0.f, 0.f, 0.f, 0.f);
    for (int p = p0; p < p1; p += 64) {
        int nb = min(64, p1 - p);            // wave-uniform
        int2 ed = (lane < nb) ? epack[p + lane] : make_int2(0, 0);
        int   srcs = ed.x;
        float nrm  = __int_as_float(ed.y);
        for (int eb = 0; eb < nb; eb += 8) { // uniform trip count
            int   sv[4];
            float nv[4];
#pragma unroll
            for (int k = 0; k < 4; ++k) {
                int e = eb + sub + 2 * k;
                int c = min(e, nb - 1);
                sv[k] = __shfl(srcs, c);
                float nr = __shfl(nrm, c);
                nv[k] = (e < nb) ? nr : 0.f;
            }
            float4 v[4];
#pragma unroll
            for (int k = 0; k < 4; ++k)
                v[k] = *(const float4*)(h2 + (size_t)sv[k] * 128 + fl * 4);
#pragma unroll
            for (int k = 0; k < 4; ++k) {
                acc[k].x += nv[k] * v[k].x; acc[k].y += nv[k] * v[k].y;
                acc[k].z += nv[k] * v[k].z; acc[k].w += nv[k] * v[k].w;
            }
        }
    }
    float4 a = acc[0];
    a.x += acc[1].x + acc[2].x + acc[3].x;
    a.y += acc[1].y + acc[2].y + acc[3].y;
    a.z += acc[1].z + acc[2].z + acc[3].z;
    a.w += acc[1].w + acc[2].w + acc[3].w;
    a.x += __shfl_xor(a.x, 32);
    a.y += __shfl_xor(a.y, 32);
    a.z += __shfl_xor(a.z, 32);
    a.w += __shfl_xor(a.w, 32);
    if (sub == 0) {
        float4 b4 = *(const float4*)(bias + fl * 4);
        float v0 = a.x + b4.x, v1 = a.y + b4.y;
        float v2 = a.z + b4.z, v3 = a.w + b4.w;
        if (apply_gelu) {
            v0 = gelu_f(v0); v1 = gelu_f(v1); v2 = gelu_f(v2); v3 = gelu_f(v3);
        }
        *(float4*)(out + (size_t)dst * 128 + fl * 4) = make_float4(v0, v1, v2, v3);
    }
}

__global__ __launch_bounds__(256) void gna_agg(const float* __restrict__ t,
                                               const float* __restrict__ ta,
                                               const int* __restrict__ ptrb,
                                               const int2* __restrict__ epack,
                                               const float* __restrict__ base,
                                               float* __restrict__ gout) {
    int dst  = (blockIdx.x * 256 + threadIdx.x) >> 6;
    int lane = threadIdx.x & 63;
    if (dst >= N_NODES) return;
    int p0 = ptrb[dst], p1 = ptrb[dst + 1];
    float tac = ta[dst];
    int sub = lane >> 4;
    int fl  = lane & 15;
    float se = 0.f;
    float4 m[4];
#pragma unroll
    for (int k = 0; k < 4; ++k) m[k] = make_float4(0.f, 0.f, 0.f, 0.f);
    for (int p = p0; p < p1; p += 64) {
        int nb = min(64, p1 - p);            // wave-uniform
        int2 ed = (lane < nb) ? epack[p + lane] : make_int2(0, 0);
        int srcs = ed.x;
        float tav = (lane < nb) ? ta[srcs] : tac;
        float ev  = expf(tac - tav);         // wave-wide: 64 exps in one go
        if (lane < nb) se += ev;
        for (int eb = 0; eb < nb; eb += 16) { // uniform trip count
            int   sv[4];
            float wv[4];
#pragma unroll
            for (int k = 0; k < 4; ++k) {
                int e = eb + sub + 4 * k;
                int c = min(e, nb - 1);
                sv[k] = __shfl(srcs, c);
                float wr = __shfl(ev, c);
                wv[k] = (e < nb) ? wr : 0.f;
            }
            float4 v[4];
#pragma unroll
            for (int k = 0; k < 4; ++k)
                v[k] = *(const float4*)(t + (size_t)sv[k] * 64 + fl * 4);
#pragma unroll
            for (int k = 0; k < 4; ++k) {
                m[k].x += wv[k] * v[k].x; m[k].y += wv[k] * v[k].y;
                m[k].z += wv[k] * v[k].z; m[k].w += wv[k] * v[k].w;
            }
        }
    }
#pragma unroll
    for (int off = 1; off < 64; off <<= 1) se += __shfl_xor(se, off);
    float4 mm = m[0];
    mm.x += m[1].x + m[2].x + m[3].x;
    mm.y += m[1].y + m[2].y + m[3].y;
    mm.z += m[1].z + m[2].z + m[3].z;
    mm.w += m[1].w + m[2].w + m[3].w;
#pragma unroll
    for (int off = 16; off <= 32; off <<= 1) {
        mm.x += __shfl_xor(mm.x, off);
        mm.y += __shfl_xor(mm.y, off);
        mm.z += __shfl_xor(mm.z, off);
        mm.w += __shfl_xor(mm.w, off);
    }
    if (lane < 16) {
        float winv = 1.0f / (se + 1e-16f);
        float4 bs = *(const float4*)(base + (size_t)dst * 64 + fl * 4);
        float v0 = bs.x + mm.x * winv;
        float v1 = bs.y + mm.y * winv;
        float v2 = bs.z + mm.z * winv;
        float v3 = bs.w + mm.w * winv;
        *(float4*)(gout + (size_t)dst * 64 + fl * 4) =
            make_float4(gelu_f(v0), gelu_f(v1), gelu_f(v2), gelu_f(v3));
    }
}

// ---------------- launch ----------------

extern "C" void kernel_launch(void* const* d_in, const int* in_sizes, int n_in,
                              void* d_out, int out_size, void* d_ws, size_t ws_size,
                              hipStream_t stream) {
    const float* x     = (const float*)d_in[0];
    const float* s     = (const float*)d_in[1];
    const int*   ei    = (const int*)d_in[2];
    const float* gcn_W = (const float*)d_in[3];
    const float* gcn_b = (const float*)d_in[4];
    const float* w1W   = (const float*)d_in[5];
    const float* w1b   = (const float*)d_in[6];
    const float* w2W   = (const float*)d_in[7];
    const float* w2b   = (const float*)d_in[8];
    const float* ga    = (const float*)d_in[9];

    float* h_out = (float*)d_out;                               // N x 128
    float* g_out = (float*)d_out + (size_t)N_NODES * 128;       // N x 64

    size_t off = 0;
    char* wsb = (char*)d_ws;
    auto take = [&](size_t bytes) {
        void* p = wsb + off;
        off = (off + bytes + 255) & ~(size_t)255;
        return p;
    };
    int*   cnt     = (int*)take((size_t)N_NODES * 4);
    int*   ptrb    = (int*)take((size_t)(N_NODES + 1) * 4);
    int*   aux     = (int*)take((size_t)ET * 4);
    float* dinv    = (float*)take((size_t)N_NODES * 4);
    int2*  epack   = (int2*)take((size_t)ET * 8);
    float* h2      = (float*)take((size_t)N_NODES * 128 * 4);
    float* tbuf    = (float*)take((size_t)N_NODES * 64 * 4);
    float* basebuf = (float*)take((size_t)N_NODES * 64 * 4);
    float* tabuf   = (float*)take((size_t)N_NODES * 4);
    int*   bsum    = (int*)take((size_t)NB_SCAN * 4);
    (void)ws_size; (void)in_sizes; (void)n_in; (void)out_size;

    const int* erow = ei;
    const int* ecol = ei + E_EDGES;

    hipMemsetAsync(cnt, 0, (size_t)N_NODES * 4, stream);

    int ge = (ET + 255) / 256;
    count_pos<<<ge, 256, 0, stream>>>(ecol, cnt, aux);
    scan_part1<<<NB_SCAN, 256, 0, stream>>>(cnt, bsum);
    scan_part2<<<1, 256, 0, stream>>>(bsum);
    scan_part3<<<NB_SCAN, 256, 0, stream>>>(cnt, bsum, ptrb, dinv);
    bucket<<<ge, 256, 0, stream>>>(erow, ecol, aux, ptrb, dinv, epack);

    const int mf_blocks   = (N_NODES + 63) / 64;         // 782
    const int wave_blocks = (N_NODES * 64 + 255) / 256;  // 12500

    // ---- GCN ----
    const float* hin = x;
    for (int l = 0; l < L_LAYERS; ++l) {
        gemm_mfma<<<mf_blocks, 256, 0, stream>>>(
            hin, 128, gcn_W + (size_t)l * 128 * 128,
            nullptr, nullptr, nullptr, nullptr,
            h2, nullptr, nullptr, 0);
        agg128<<<wave_blocks, 256, 0, stream>>>(h2, ptrb, epack,
                                                gcn_b + (size_t)l * 128, h_out,
                                                (l < L_LAYERS - 1) ? 1 : 0);
        hin = h_out;
    }

    // ---- GNA ----
    const float* gin = s;
    for (int l = 0; l < L_LAYERS; ++l) {
        gemm_mfma<<<mf_blocks, 256, 0, stream>>>(
            gin, 64, w1W + (size_t)l * 64 * 64, w2W + (size_t)l * 64 * 64,
            w1b + (size_t)l * 64, w2b + (size_t)l * 64, ga + (size_t)l * 64,
            basebuf, tbuf, tabuf, 1);
        gna_agg<<<wave_blocks, 256, 0, stream>>>(tbuf, tabuf, ptrb, epack, basebuf, g_out);
        gin = g_out;
    }
}

// Round 8
// 656.602 us; speedup vs baseline: 1.1496x; 1.1496x over previous
//
#include <hip/hip_runtime.h>
#include <math.h>

#define N_NODES 50000
#define E_EDGES 800000
#define ET (E_EDGES + N_NODES)   // edges + self loops
#define L_LAYERS 4
#define NB_SCAN ((N_NODES + 255) / 256)   // 196

typedef __attribute__((ext_vector_type(8))) short short8;
typedef __attribute__((ext_vector_type(4))) float f32x4;

__device__ __forceinline__ float gelu_f(float x) {
    return 0.5f * x * (1.0f + erff(x * 0.70710678118654752f));
}

__device__ __forceinline__ void split_hl(float x, unsigned short& h, unsigned short& lo) {
    unsigned u = __float_as_uint(x);
    h = (unsigned short)(u >> 16);
    float hif = __uint_as_float(u & 0xffff0000u);
    lo = (unsigned short)(__float_as_uint(x - hif) >> 16);
}

// ---------------- graph preprocessing ----------------

__global__ __launch_bounds__(256) void count_pos(const int* __restrict__ ecol,
                                                 int* __restrict__ cnt,
                                                 int* __restrict__ aux) {
    int e = blockIdx.x * 256 + threadIdx.x;
    if (e >= ET) return;
    int c = (e < E_EDGES) ? ecol[e] : (e - E_EDGES);
    aux[e] = atomicAdd(&cnt[c], 1);
}

__global__ __launch_bounds__(256) void scan_part1(const int* __restrict__ cnt,
                                                  int* __restrict__ bsum) {
    __shared__ int red[256];
    int t = threadIdx.x;
    int i = blockIdx.x * 256 + t;
    red[t] = (i < N_NODES) ? cnt[i] : 0;
    __syncthreads();
#pragma unroll
    for (int off = 128; off; off >>= 1) {
        if (t < off) red[t] += red[t + off];
        __syncthreads();
    }
    if (t == 0) bsum[blockIdx.x] = red[0];
}

__global__ __launch_bounds__(256) void scan_part2(int* __restrict__ bsum) {
    __shared__ int sh[256];
    int t = threadIdx.x;
    int v = (t < NB_SCAN) ? bsum[t] : 0;
    sh[t] = v;
    __syncthreads();
    for (int off = 1; off < 256; off <<= 1) {
        int u = (t >= off) ? sh[t - off] : 0;
        __syncthreads();
        sh[t] += u;
        __syncthreads();
    }
    if (t < NB_SCAN) bsum[t] = sh[t] - v;   // exclusive
}

__global__ __launch_bounds__(256) void scan_part3(const int* __restrict__ cnt,
                                                  const int* __restrict__ bsum,
                                                  int* __restrict__ ptrb,
                                                  float* __restrict__ dinv) {
    __shared__ int sh[256];
    int t = threadIdx.x;
    int i = blockIdx.x * 256 + t;
    int v = (i < N_NODES) ? cnt[i] : 0;
    sh[t] = v;
    __syncthreads();
    for (int off = 1; off < 256; off <<= 1) {
        int u = (t >= off) ? sh[t - off] : 0;
        __syncthreads();
        sh[t] += u;
        __syncthreads();
    }
    int excl = sh[t] - v + bsum[blockIdx.x];
    if (i < N_NODES) {
        ptrb[i] = excl;
        dinv[i] = rsqrtf((float)v);   // deg >= 1 (self loop)
    }
    if (i == N_NODES - 1) ptrb[N_NODES] = excl + v;
}

__global__ __launch_bounds__(256) void bucket(const int* __restrict__ erow,
                                              const int* __restrict__ ecol,
                                              const int* __restrict__ aux,
                                              const int* __restrict__ ptrb,
                                              const float* __restrict__ dinv,
                                              int2* __restrict__ epack) {
    int e = blockIdx.x * 256 + threadIdx.x;
    if (e >= ET) return;
    int r, c;
    if (e < E_EDGES) { r = erow[e]; c = ecol[e]; }
    else             { r = e - E_EDGES; c = r; }
    int pos = ptrb[c] + aux[e];
    epack[pos] = make_int2(r, __float_as_int(dinv[r] * dinv[c]));
}

// ---------------- W pre-layout: hi/lo bf16 in B-fragment lane order ----------------
// Fragment: B[k = q*8+j][n], lane = q*16+n. Storage [layer][s][nt][lane][j], 16B/lane.
// gcn: s=0..3 (K=128), nt=0..7 (N=128).  gna: s=0..1 (K=64), nt=0..7 (w1 cols|w2 cols).

__global__ __launch_bounds__(256) void prep_w(const float* __restrict__ gcn_W,
                                              const float* __restrict__ w1W,
                                              const float* __restrict__ w2W,
                                              unsigned short* __restrict__ gf_hi,
                                              unsigned short* __restrict__ gf_lo,
                                              unsigned short* __restrict__ nf_hi,
                                              unsigned short* __restrict__ nf_lo) {
    int idx = blockIdx.x * 256 + threadIdx.x;
    if (idx < 8192) {                       // gcn: 4 layer x 4 s x 8 nt x 64 lane
        int lane = idx & 63, nt = (idx >> 6) & 7, s = (idx >> 9) & 3, layer = idx >> 11;
        int q = lane >> 4, n = lane & 15;
        const float* W = gcn_W + (size_t)layer * 128 * 128;
        size_t o = (size_t)idx * 8;
#pragma unroll
        for (int j = 0; j < 8; ++j) {
            float x = W[(size_t)(s * 32 + q * 8 + j) * 128 + nt * 16 + n];
            unsigned short h, lo;
            split_hl(x, h, lo);
            gf_hi[o + j] = h; gf_lo[o + j] = lo;
        }
    } else if (idx < 8192 + 4096) {         // gna: 4 layer x 2 s x 8 nt x 64 lane
        int t = idx - 8192;
        int lane = t & 63, nt = (t >> 6) & 7, s = (t >> 9) & 1, layer = t >> 10;
        int q = lane >> 4, n = lane & 15;
        int col = nt * 16 + n;              // <64 -> w1, >=64 -> w2
        const float* W = (col < 64) ? (w1W + (size_t)layer * 64 * 64)
                                    : (w2W + (size_t)layer * 64 * 64);
        int c = col & 63;
        size_t o = (size_t)t * 8;
#pragma unroll
        for (int j = 0; j < 8; ++j) {
            float x = W[(size_t)(s * 32 + q * 8 + j) * 64 + c];
            unsigned short h, lo;
            split_hl(x, h, lo);
            nf_hi[o + j] = h; nf_lo[o + j] = lo;
        }
    }
}

// ---------------- MFMA GEMM, LDS-free (bf16 hi/lo split, f32-class accuracy) ----
// D = Ahi*Whi + Ahi*Wlo + Alo*Whi  (error ~2^-16 rel)
// Each wave owns 16 rows; A fragments loaded direct from global and split
// in-register; W fragments read direct from the pre-layouted arrays (L2-hot
// broadcast). No LDS, no barriers.
// mode 0: O1 = A@W (K=128, N=128)     mode 1: O1=A@W1+b1, O2=A@W2+b2, ta=O2@avec

__global__ __launch_bounds__(256) void gemm_mfma(
    const float* __restrict__ A, int Kfull,
    const unsigned short* __restrict__ wf_hi, const unsigned short* __restrict__ wf_lo,
    const float* __restrict__ b1, const float* __restrict__ b2,
    const float* __restrict__ avec,
    float* __restrict__ O1, float* __restrict__ O2, float* __restrict__ ta,
    int mode) {
    int tid = threadIdx.x;
    int w  = tid >> 6;
    int l  = tid & 63;
    int lq = l >> 4;
    int ln = l & 15;
    int m0 = blockIdx.x * 64;
    int arow = m0 + w * 16 + ln;            // row this lane's A fragment covers
    bool avalid = arow < N_NODES;
    const int nsteps = Kfull >> 5;          // 4 (K=128) or 2 (K=64)

    f32x4 acc[8];
#pragma unroll
    for (int i = 0; i < 8; ++i) acc[i] = (f32x4){0.f, 0.f, 0.f, 0.f};

    for (int s = 0; s < nsteps; ++s) {
        float4 a0 = make_float4(0.f, 0.f, 0.f, 0.f);
        float4 a1 = make_float4(0.f, 0.f, 0.f, 0.f);
        if (avalid) {
            const float* ap = A + (size_t)arow * Kfull + s * 32 + lq * 8;
            a0 = *(const float4*)ap;
            a1 = *(const float4*)(ap + 4);
        }
        float xs[8] = {a0.x, a0.y, a0.z, a0.w, a1.x, a1.y, a1.z, a1.w};
        short8 ah, al;
#pragma unroll
        for (int c = 0; c < 8; ++c) {
            unsigned short h, lo;
            split_hl(xs[c], h, lo);
            ah[c] = (short)h; al[c] = (short)lo;
        }
#pragma unroll
        for (int nt = 0; nt < 8; ++nt) {
            size_t fo = ((size_t)(s * 8 + nt) * 64 + l) * 8;
            short8 wh = *(const short8*)(wf_hi + fo);
            short8 wl = *(const short8*)(wf_lo + fo);
            acc[nt] = __builtin_amdgcn_mfma_f32_16x16x32_bf16(ah, wh, acc[nt], 0, 0, 0);
            acc[nt] = __builtin_amdgcn_mfma_f32_16x16x32_bf16(ah, wl, acc[nt], 0, 0, 0);
            acc[nt] = __builtin_amdgcn_mfma_f32_16x16x32_bf16(al, wh, acc[nt], 0, 0, 0);
        }
    }

    // C layout: col = ln (per nt tile), row-in-tile = lq*4 + r  (verified R7)
    if (mode == 0) {
#pragma unroll
        for (int nt = 0; nt < 8; ++nt) {
            int col = nt * 16 + ln;
#pragma unroll
            for (int r = 0; r < 4; ++r) {
                int row = m0 + w * 16 + lq * 4 + r;
                if (row < N_NODES) O1[(size_t)row * 128 + col] = acc[nt][r];
            }
        }
    } else {
        float pa[4] = {0.f, 0.f, 0.f, 0.f};
#pragma unroll
        for (int nt = 0; nt < 4; ++nt) {
            int col = nt * 16 + ln;
            float bb = b1[col];
#pragma unroll
            for (int r = 0; r < 4; ++r) {
                int row = m0 + w * 16 + lq * 4 + r;
                if (row < N_NODES) O1[(size_t)row * 64 + col] = acc[nt][r] + bb;
            }
        }
#pragma unroll
        for (int nt = 4; nt < 8; ++nt) {
            int col = (nt - 4) * 16 + ln;
            float bb = b2[col];
            float av = avec[col];
#pragma unroll
            for (int r = 0; r < 4; ++r) {
                float t2 = acc[nt][r] + bb;
                int row = m0 + w * 16 + lq * 4 + r;
                if (row < N_NODES) O2[(size_t)row * 64 + col] = t2;
                pa[r] += t2 * av;
            }
        }
#pragma unroll
        for (int r = 0; r < 4; ++r) {
            pa[r] += __shfl_xor(pa[r], 1);
            pa[r] += __shfl_xor(pa[r], 2);
            pa[r] += __shfl_xor(pa[r], 4);
            pa[r] += __shfl_xor(pa[r], 8);
            int row = m0 + w * 16 + lq * 4 + r;
            if (ln == 0 && row < N_NODES) ta[row] = pa[r];
        }
    }
}

// ---------------- edge aggregation (one wave per dst) ----------------

__global__ __launch_bounds__(256) void agg128(const float* __restrict__ h2,
                                              const int* __restrict__ ptrb,
                                              const int2* __restrict__ epack,
                                              const float* __restrict__ bias,
                                              float* __restrict__ out,
                                              int apply_gelu) {
    int dst  = (blockIdx.x * 256 + threadIdx.x) >> 6;
    int lane = threadIdx.x & 63;
    if (dst >= N_NODES) return;
    int sub = lane >> 5;
    int fl  = lane & 31;
    int p0 = ptrb[dst], p1 = ptrb[dst + 1];
    float4 acc[4];
#pragma unroll
    for (int k = 0; k < 4; ++k) acc[k] = make_float4(0.f, 0.f, 0.f, 0.f);
    for (int p = p0; p < p1; p += 64) {
        int nb = min(64, p1 - p);            // wave-uniform
        int2 ed = (lane < nb) ? epack[p + lane] : make_int2(0, 0);
        int   srcs = ed.x;
        float nrm  = __int_as_float(ed.y);
        for (int eb = 0; eb < nb; eb += 8) { // uniform trip count
            int   sv[4];
            float nv[4];
#pragma unroll
            for (int k = 0; k < 4; ++k) {
                int e = eb + sub + 2 * k;
                int c = min(e, nb - 1);
                sv[k] = __shfl(srcs, c);
                float nr = __shfl(nrm, c);
                nv[k] = (e < nb) ? nr : 0.f;
            }
            float4 v[4];
#pragma unroll
            for (int k = 0; k < 4; ++k)
                v[k] = *(const float4*)(h2 + (size_t)sv[k] * 128 + fl * 4);
#pragma unroll
            for (int k = 0; k < 4; ++k) {
                acc[k].x += nv[k] * v[k].x; acc[k].y += nv[k] * v[k].y;
                acc[k].z += nv[k] * v[k].z; acc[k].w += nv[k] * v[k].w;
            }
        }
    }
    float4 a = acc[0];
    a.x += acc[1].x + acc[2].x + acc[3].x;
    a.y += acc[1].y + acc[2].y + acc[3].y;
    a.z += acc[1].z + acc[2].z + acc[3].z;
    a.w += acc[1].w + acc[2].w + acc[3].w;
    a.x += __shfl_xor(a.x, 32);
    a.y += __shfl_xor(a.y, 32);
    a.z += __shfl_xor(a.z, 32);
    a.w += __shfl_xor(a.w, 32);
    if (sub == 0) {
        float4 b4 = *(const float4*)(bias + fl * 4);
        float v0 = a.x + b4.x, v1 = a.y + b4.y;
        float v2 = a.z + b4.z, v3 = a.w + b4.w;
        if (apply_gelu) {
            v0 = gelu_f(v0); v1 = gelu_f(v1); v2 = gelu_f(v2); v3 = gelu_f(v3);
        }
        *(float4*)(out + (size_t)dst * 128 + fl * 4) = make_float4(v0, v1, v2, v3);
    }
}

__global__ __launch_bounds__(256) void gna_agg(const float* __restrict__ t,
                                               const float* __restrict__ ta,
                                               const int* __restrict__ ptrb,
                                               const int2* __restrict__ epack,
                                               const float* __restrict__ base,
                                               float* __restrict__ gout) {
    int dst  = (blockIdx.x * 256 + threadIdx.x) >> 6;
    int lane = threadIdx.x & 63;
    if (dst >= N_NODES) return;
    int p0 = ptrb[dst], p1 = ptrb[dst + 1];
    float tac = ta[dst];
    int sub = lane >> 4;
    int fl  = lane & 15;
    float se = 0.f;
    float4 m[4];
#pragma unroll
    for (int k = 0; k < 4; ++k) m[k] = make_float4(0.f, 0.f, 0.f, 0.f);
    for (int p = p0; p < p1; p += 64) {
        int nb = min(64, p1 - p);            // wave-uniform
        int2 ed = (lane < nb) ? epack[p + lane] : make_int2(0, 0);
        int srcs = ed.x;
        float tav = (lane < nb) ? ta[srcs] : tac;
        float ev  = expf(tac - tav);         // wave-wide: 64 exps in one go
        if (lane < nb) se += ev;
        for (int eb = 0; eb < nb; eb += 16) { // uniform trip count
            int   sv[4];
            float wv[4];
#pragma unroll
            for (int k = 0; k < 4; ++k) {
                int e = eb + sub + 4 * k;
                int c = min(e, nb - 1);
                sv[k] = __shfl(srcs, c);
                float wr = __shfl(ev, c);
                wv[k] = (e < nb) ? wr : 0.f;
            }
            float4 v[4];
#pragma unroll
            for (int k = 0; k < 4; ++k)
                v[k] = *(const float4*)(t + (size_t)sv[k] * 64 + fl * 4);
#pragma unroll
            for (int k = 0; k < 4; ++k) {
                m[k].x += wv[k] * v[k].x; m[k].y += wv[k] * v[k].y;
                m[k].z += wv[k] * v[k].z; m[k].w += wv[k] * v[k].w;
            }
        }
    }
#pragma unroll
    for (int off = 1; off < 64; off <<= 1) se += __shfl_xor(se, off);
    float4 mm = m[0];
    mm.x += m[1].x + m[2].x + m[3].x;
    mm.y += m[1].y + m[2].y + m[3].y;
    mm.z += m[1].z + m[2].z + m[3].z;
    mm.w += m[1].w + m[2].w + m[3].w;
#pragma unroll
    for (int off = 16; off <= 32; off <<= 1) {
        mm.x += __shfl_xor(mm.x, off);
        mm.y += __shfl_xor(mm.y, off);
        mm.z += __shfl_xor(mm.z, off);
        mm.w += __shfl_xor(mm.w, off);
    }
    if (lane < 16) {
        float winv = 1.0f / (se + 1e-16f);
        float4 bs = *(const float4*)(base + (size_t)dst * 64 + fl * 4);
        float v0 = bs.x + mm.x * winv;
        float v1 = bs.y + mm.y * winv;
        float v2 = bs.z + mm.z * winv;
        float v3 = bs.w + mm.w * winv;
        *(float4*)(gout + (size_t)dst * 64 + fl * 4) =
            make_float4(gelu_f(v0), gelu_f(v1), gelu_f(v2), gelu_f(v3));
    }
}

// ---------------- launch ----------------

extern "C" void kernel_launch(void* const* d_in, const int* in_sizes, int n_in,
                              void* d_out, int out_size, void* d_ws, size_t ws_size,
                              hipStream_t stream) {
    const float* x     = (const float*)d_in[0];
    const float* s     = (const float*)d_in[1];
    const int*   ei    = (const int*)d_in[2];
    const float* gcn_W = (const float*)d_in[3];
    const float* gcn_b = (const float*)d_in[4];
    const float* w1W   = (const float*)d_in[5];
    const float* w1b   = (const float*)d_in[6];
    const float* w2W   = (const float*)d_in[7];
    const float* w2b   = (const float*)d_in[8];
    const float* ga    = (const float*)d_in[9];

    float* h_out = (float*)d_out;                               // N x 128
    float* g_out = (float*)d_out + (size_t)N_NODES * 128;       // N x 64

    size_t off = 0;
    char* wsb = (char*)d_ws;
    auto take = [&](size_t bytes) {
        void* p = wsb + off;
        off = (off + bytes + 255) & ~(size_t)255;
        return p;
    };
    int*   cnt     = (int*)take((size_t)N_NODES * 4);
    int*   ptrb    = (int*)take((size_t)(N_NODES + 1) * 4);
    int*   aux     = (int*)take((size_t)ET * 4);
    float* dinv    = (float*)take((size_t)N_NODES * 4);
    int2*  epack   = (int2*)take((size_t)ET * 8);
    float* h2      = (float*)take((size_t)N_NODES * 128 * 4);
    float* tbuf    = (float*)take((size_t)N_NODES * 64 * 4);
    float* basebuf = (float*)take((size_t)N_NODES * 64 * 4);
    float* tabuf   = (float*)take((size_t)N_NODES * 4);
    int*   bsum    = (int*)take((size_t)NB_SCAN * 4);
    unsigned short* gf_hi = (unsigned short*)take((size_t)8192 * 8 * 2);
    unsigned short* gf_lo = (unsigned short*)take((size_t)8192 * 8 * 2);
    unsigned short* nf_hi = (unsigned short*)take((size_t)4096 * 8 * 2);
    unsigned short* nf_lo = (unsigned short*)take((size_t)4096 * 8 * 2);
    (void)ws_size; (void)in_sizes; (void)n_in; (void)out_size;

    const int* erow = ei;
    const int* ecol = ei + E_EDGES;

    hipMemsetAsync(cnt, 0, (size_t)N_NODES * 4, stream);

    int ge = (ET + 255) / 256;
    count_pos<<<ge, 256, 0, stream>>>(ecol, cnt, aux);
    scan_part1<<<NB_SCAN, 256, 0, stream>>>(cnt, bsum);
    scan_part2<<<1, 256, 0, stream>>>(bsum);
    scan_part3<<<NB_SCAN, 256, 0, stream>>>(cnt, bsum, ptrb, dinv);
    bucket<<<ge, 256, 0, stream>>>(erow, ecol, aux, ptrb, dinv, epack);
    prep_w<<<48, 256, 0, stream>>>(gcn_W, w1W, w2W, gf_hi, gf_lo, nf_hi, nf_lo);

    const int mf_blocks   = (N_NODES + 63) / 64;         // 782
    const int wave_blocks = (N_NODES * 64 + 255) / 256;  // 12500

    // ---- GCN ----
    const float* hin = x;
    for (int l = 0; l < L_LAYERS; ++l) {
        gemm_mfma<<<mf_blocks, 256, 0, stream>>>(
            hin, 128,
            gf_hi + (size_t)l * 4 * 8 * 64 * 8, gf_lo + (size_t)l * 4 * 8 * 64 * 8,
            nullptr, nullptr, nullptr,
            h2, nullptr, nullptr, 0);
        agg128<<<wave_blocks, 256, 0, stream>>>(h2, ptrb, epack,
                                                gcn_b + (size_t)l * 128, h_out,
                                                (l < L_LAYERS - 1) ? 1 : 0);
        hin = h_out;
    }

    // ---- GNA ----
    const float* gin = s;
    for (int l = 0; l < L_LAYERS; ++l) {
        gemm_mfma<<<mf_blocks, 256, 0, stream>>>(
            gin, 64,
            nf_hi + (size_t)l * 2 * 8 * 64 * 8, nf_lo + (size_t)l * 2 * 8 * 64 * 8,
            w1b + (size_t)l * 64, w2b + (size_t)l * 64, ga + (size_t)l * 64,
            basebuf, tbuf, tabuf, 1);
        gna_agg<<<wave_blocks, 256, 0, stream>>>(tbuf, tabuf, ptrb, epack, basebuf, g_out);
        gin = g_out;
    }
}